// Round 10
// baseline (173.408 us; speedup 1.0000x reference)
//
#include <hip/hip_runtime.h>
#include <hip/hip_bf16.h>

#define LL 2048
#define DM 512
#define SCALE 0.02209708691207961f   // 1/sqrt(2048)

typedef unsigned short u16;
typedef __attribute__((ext_vector_type(8))) short short8;    // 8 bf16 (4 VGPRs)
typedef __attribute__((ext_vector_type(4))) short short4v;   // 4 bf16 (2 VGPRs)
typedef __attribute__((ext_vector_type(4))) float f32x4;     // MFMA C/D

// ws layout (u16 element offsets), ~27 MB of the 256 MiB ws:
//  XAQ/XAK/XAV: bf16 inputs in proj-A-frag order [2][128 r16][16 kt][64 lane][8]
//  WB : bf16 weights in B-frag order [3][8][16 kt][4 nt][64 lane][8]
//  QA/KA: bf16 Q,K projections in frag order (Q pre-scaled by SCALE)
//  VB : bf16 V in PV-B-frag order (RAW; Sinv applied to P in attn via rcp)
//  S  : f32 column sums [16][2048] (atomic-accumulated; prep zeroes)
#define XAQ_OFF 0u
#define XAK_OFF 2097152u
#define XAV_OFF 4194304u
#define WB_OFF  6291456u
#define QA_OFF  7077888u
#define KA_OFF  9175040u
#define VB_OFF  11272192u
#define S_OFF   13369344u    // float region, 32768 floats

__device__ __forceinline__ u16 f2bf(float f) {
  union { float f; unsigned u; } v; v.f = f;
  unsigned r = v.u + 0x7fff + ((v.u >> 16) & 1);   // RNE
  return (u16)(r >> 16);
}
__device__ __forceinline__ size_t frag_idx(int bh, int t64, int w, int c, int lane) {
  return ((((size_t)(bh * 32 + t64) * 4 + w) * 2 + c) * 64 + lane) * 8;
}
__device__ __forceinline__ size_t vb_idx(int bh, int kt, int w, int et, int lane) {
  return ((((size_t)(bh * 32 + kt) * 4 + w) * 4 + et) * 64 + lane) * 4;
}

// ---------------- prep: X -> frag order; W -> B-frag order; zero S and out ----------------
__global__ __launch_bounds__(256) void prep_kernel(
    const float* __restrict__ queries, const float* __restrict__ keys,
    const float* __restrict__ values, const float* __restrict__ WQ,
    const float* __restrict__ WK, const float* __restrict__ WV,
    u16* __restrict__ wsb, float* __restrict__ out) {
  int t = threadIdx.x;
  int blk = blockIdx.x;
  if (blk < 768) {
    int tens = blk >> 8;                       // 0=Q,1=K,2=V
    int grp  = blk & 255;                      // b*128 + r16
    const float* src = (tens == 0 ? queries : tens == 1 ? keys : values) +
                       (size_t)grp * 16 * 512;
    __shared__ __align__(16) u16 Xs[16][520];
#pragma unroll
    for (int rep = 0; rep < 8; ++rep) {
      int f4 = t + rep * 256;                  // 0..2047
      int row = f4 >> 7, c4 = f4 & 127;
      float4 v = *(const float4*)(src + (size_t)row * 512 + c4 * 4);
      short4v o;
      o[0] = (short)f2bf(v.x); o[1] = (short)f2bf(v.y);
      o[2] = (short)f2bf(v.z); o[3] = (short)f2bf(v.w);
      *(short4v*)&Xs[row][c4 * 4] = o;
    }
    __syncthreads();
    u16* dst = wsb + (tens == 0 ? XAQ_OFF : tens == 1 ? XAK_OFF : XAV_OFF) +
               (size_t)grp * 16 * 64 * 8;
#pragma unroll
    for (int rep = 0; rep < 4; ++rep) {
      int o = t + rep * 256;                   // kt*64 + lane
      int kt = o >> 6, lane = o & 63;
      int quad = lane >> 4, l16 = lane & 15;
      short8 v = *(const short8*)&Xs[l16][kt * 32 + quad * 8];
      *(short8*)(dst + (size_t)o * 8) = v;
    }
  } else if (blk < 1152) {
    int c2 = (blk - 768) * 256 + t;            // 0..98303
    int lane = c2 & 63;
    int nt = (c2 >> 6) & 3;
    int kt = (c2 >> 8) & 15;
    int h  = (c2 >> 12) & 7;
    int z  = c2 >> 15;
    int quad = lane >> 4, l16 = lane & 15;
    const float* W = (z == 0) ? WQ : (z == 1) ? WK : WV;
    const float* src = W + ((size_t)h * DM + kt * 32 + quad * 8) * 64 + nt * 16 + l16;
    short8 o;
#pragma unroll
    for (int j = 0; j < 8; ++j) o[j] = (short)f2bf(src[(size_t)j * 64]);
    *(short8*)(wsb + WB_OFF + (size_t)c2 * 8) = o;
  } else if (blk < 1184) {
    // zero S: 32 blocks x 256 threads x 1 float4
    float* S = (float*)(wsb + S_OFF);
    int idx = (blk - 1152) * 256 + t;
    ((float4*)S)[idx] = (float4){0.f, 0.f, 0.f, 0.f};
  } else {
    // zero out: 512 blocks x 256 threads x 4 float4 = 2M floats
    float4* o4 = (float4*)out;
    int base = (blk - 1184) * 1024 + t;
#pragma unroll
    for (int rep = 0; rep < 4; ++rep)
      o4[base + rep * 256] = (float4){0.f, 0.f, 0.f, 0.f};
  }
}

// ---------------- proj: barrier-free MFMA GEMM; coalesced frag-order epilogue via LDS ----------------
__global__ __launch_bounds__(256) void proj_kernel(u16* __restrict__ wsb) {
  int t = threadIdx.x;
  int lane = t & 63, w = t >> 6, quad = lane >> 4, l16 = lane & 15;
  int z = blockIdx.z, bh = blockIdx.y, b = bh >> 3, h = bh & 7;
  int QT = blockIdx.x;

  const u16* Bw = wsb + WB_OFF + ((size_t)(z * 8 + h) * 16) * 4 * 64 * 8;
  const u16* Ab = wsb + (z == 0 ? XAQ_OFF : z == 1 ? XAK_OFF : XAV_OFF) +
      (((size_t)b * 128 + QT * 4 + w) * 16) * 64 * 8;

  f32x4 acc[4];
#pragma unroll
  for (int nt = 0; nt < 4; ++nt) acc[nt] = (f32x4){0.f, 0.f, 0.f, 0.f};

#pragma unroll 4
  for (int kt = 0; kt < 16; ++kt) {
    short8 a = *(const short8*)(Ab + ((size_t)kt * 64 + lane) * 8);
#pragma unroll
    for (int nt = 0; nt < 4; ++nt) {
      short8 bb = *(const short8*)(Bw + (((size_t)kt * 4 + nt) * 64 + lane) * 8);
      acc[nt] = __builtin_amdgcn_mfma_f32_16x16x32_bf16(a, bb, acc[nt], 0, 0, 0);
    }
  }

  __shared__ float Cs[64][68];
  float sc = (z == 0) ? SCALE : 1.0f;
#pragma unroll
  for (int nt = 0; nt < 4; ++nt)
#pragma unroll
    for (int r = 0; r < 4; ++r)
      Cs[w * 16 + quad * 4 + r][nt * 16 + l16] = acc[nt][r] * sc;
  __syncthreads();

  if (z < 2) {
    u16* base = wsb + (z == 0 ? QA_OFF : KA_OFF);
#pragma unroll
    for (int c = 0; c < 2; ++c) {
      const float* srcr = &Cs[w * 16 + l16][c * 32 + quad * 8];
      short8 o;
#pragma unroll
      for (int j = 0; j < 8; ++j) o[j] = (short)f2bf(srcr[j]);
      *(short8*)(base + frag_idx(bh, QT, w, c, lane)) = o;
    }
  } else {
#pragma unroll
    for (int et = 0; et < 4; ++et) {
      short4v o;
#pragma unroll
      for (int j = 0; j < 4; ++j)
        o[j] = (short)f2bf(Cs[w * 16 + quad * 4 + j][et * 16 + l16]);
      *(short4v*)(wsb + VB_OFF + vb_idx(bh, QT, w, et, lane)) = o;
    }
  }
}

// ---------------- stats: q-split x2; atomicAdd column sums into S ----------------
// grid (x=bh, y=KT, z=qs): linear%8 == bh%8 -> all blocks of a bh on one XCD.
__global__ __launch_bounds__(256, 4) void stats_kernel(u16* __restrict__ wsb) {
  int t = threadIdx.x;
  int lane = t & 63, w = t >> 6, quad = lane >> 4, l16 = lane & 15;
  int bh = blockIdx.x;
  int KT = blockIdx.y;
  int qs = blockIdx.z;

  short8 ka[4][2];
#pragma unroll
  for (int mt = 0; mt < 4; ++mt)
#pragma unroll
    for (int c = 0; c < 2; ++c)
      ka[mt][c] = *(const short8*)(wsb + KA_OFF + frag_idx(bh, KT, mt, c, lane));

  float rs[4][4];
#pragma unroll
  for (int mt = 0; mt < 4; ++mt)
#pragma unroll
    for (int r = 0; r < 4; ++r) rs[mt][r] = 0.f;

  for (int qt = qs * 16; qt < qs * 16 + 16; ++qt) {
    short8 qb0 = *(const short8*)(wsb + QA_OFF + frag_idx(bh, qt, w, 0, lane));
    short8 qb1 = *(const short8*)(wsb + QA_OFF + frag_idx(bh, qt, w, 1, lane));
#pragma unroll
    for (int mt = 0; mt < 4; ++mt) {
      f32x4 y = (f32x4){0.f, 0.f, 0.f, 0.f};
      y = __builtin_amdgcn_mfma_f32_16x16x32_bf16(ka[mt][0], qb0, y, 0, 0, 0);
      y = __builtin_amdgcn_mfma_f32_16x16x32_bf16(ka[mt][1], qb1, y, 0, 0, 0);
#pragma unroll
      for (int r = 0; r < 4; ++r) rs[mt][r] += __expf(y[r]);
    }
  }
#pragma unroll
  for (int mt = 0; mt < 4; ++mt)
#pragma unroll
    for (int r = 0; r < 4; ++r) {
      rs[mt][r] += __shfl_xor(rs[mt][r], 1);
      rs[mt][r] += __shfl_xor(rs[mt][r], 2);
      rs[mt][r] += __shfl_xor(rs[mt][r], 4);
      rs[mt][r] += __shfl_xor(rs[mt][r], 8);
    }

  __shared__ float Sred[4][64];
  if (l16 == 0) {
#pragma unroll
    for (int mt = 0; mt < 4; ++mt)
#pragma unroll
      for (int r = 0; r < 4; ++r)
        Sred[w][mt * 16 + quad * 4 + r] = rs[mt][r];
  }
  __syncthreads();
  if (t < 64) {
    float s = Sred[0][t] + Sred[1][t] + Sred[2][t] + Sred[3][t];
    float* S = (float*)(wsb + S_OFF);
    atomicAdd(&S[(size_t)bh * LL + KT * 64 + t], s);
  }
}

// ---------------- attn: k-split x2; P = exp(y)*rcp(S) in regs; atomicAdd into out ----------------
// grid (x=bh, y=QT, z=ks): linear%8 == bh%8 -> XCD-local KA/VB/QA re-reads.
__global__ __launch_bounds__(256, 3) void attn_kernel(const u16* __restrict__ wsb,
                                                      float* __restrict__ out) {
  int t = threadIdx.x;
  int lane = t & 63, w = t >> 6, quad = lane >> 4, l16 = lane & 15;
  int bh = blockIdx.x, b = bh >> 3, h = bh & 7;
  int QT = blockIdx.y, qbase = QT * 64;
  int ks = blockIdx.z;
  const float* S = (const float*)(wsb + S_OFF) + (size_t)bh * LL;

  short8 qf[4][2];
#pragma unroll
  for (int nt = 0; nt < 4; ++nt)
#pragma unroll
    for (int c = 0; c < 2; ++c)
      qf[nt][c] = *(const short8*)(wsb + QA_OFF + frag_idx(bh, QT, nt, c, lane));

  f32x4 oacc[4][4];
#pragma unroll
  for (int nt = 0; nt < 4; ++nt)
#pragma unroll
    for (int et = 0; et < 4; ++et) oacc[nt][et] = (f32x4){0.f, 0.f, 0.f, 0.f};

  for (int kt = ks * 16; kt < ks * 16 + 16; ++kt) {
    short8 ka0 = *(const short8*)(wsb + KA_OFF + frag_idx(bh, kt, w, 0, lane));
    short8 ka1 = *(const short8*)(wsb + KA_OFF + frag_idx(bh, kt, w, 1, lane));
    short4v vb[4];
#pragma unroll
    for (int et = 0; et < 4; ++et)
      vb[et] = *(const short4v*)(wsb + VB_OFF + vb_idx(bh, kt, w, et, lane));
    float4 s4 = *(const float4*)(S + kt * 64 + w * 16 + quad * 4);
    float si[4];
    si[0] = __builtin_amdgcn_rcpf(s4.x);
    si[1] = __builtin_amdgcn_rcpf(s4.y);
    si[2] = __builtin_amdgcn_rcpf(s4.z);
    si[3] = __builtin_amdgcn_rcpf(s4.w);

#pragma unroll
    for (int nt = 0; nt < 4; ++nt) {
      f32x4 y = (f32x4){0.f, 0.f, 0.f, 0.f};
      y = __builtin_amdgcn_mfma_f32_16x16x32_bf16(ka0, qf[nt][0], y, 0, 0, 0);
      y = __builtin_amdgcn_mfma_f32_16x16x32_bf16(ka1, qf[nt][1], y, 0, 0, 0);
      short4v pa;
      pa[0] = (short)f2bf(__expf(y[0]) * si[0]);
      pa[1] = (short)f2bf(__expf(y[1]) * si[1]);
      pa[2] = (short)f2bf(__expf(y[2]) * si[2]);
      pa[3] = (short)f2bf(__expf(y[3]) * si[3]);
#pragma unroll
      for (int et = 0; et < 4; ++et)
        oacc[nt][et] = __builtin_amdgcn_mfma_f32_16x16x16bf16_1k(pa, vb[et], oacc[nt][et], 0, 0, 0);
    }
  }

  // 2-stage cross-wave k-reduction in 34.8 KB LDS (3 blocks/CU)
  __shared__ float red[2][64][68];
  if (w >= 2) {
#pragma unroll
    for (int nt = 0; nt < 4; ++nt)
#pragma unroll
      for (int et = 0; et < 4; ++et)
#pragma unroll
        for (int r = 0; r < 4; ++r)
          red[w - 2][nt * 16 + quad * 4 + r][et * 16 + l16] = oacc[nt][et][r];
  }
  __syncthreads();
  if (w < 2) {
#pragma unroll
    for (int nt = 0; nt < 4; ++nt)
#pragma unroll
      for (int et = 0; et < 4; ++et)
#pragma unroll
        for (int r = 0; r < 4; ++r) {
          float* p = &red[w][nt * 16 + quad * 4 + r][et * 16 + l16];
          *p += oacc[nt][et][r];
        }
  }
  __syncthreads();
  float* og = out + ((size_t)b * LL + qbase + w * 16) * 512 + h * 64;
#pragma unroll
  for (int i = 0; i < 16; ++i) {
    float s = red[0][w * 16 + i][lane] + red[1][w * 16 + i][lane];
    atomicAdd(&og[(size_t)i * 512 + lane], s);
  }
}

extern "C" void kernel_launch(void* const* d_in, const int* in_sizes, int n_in,
                              void* d_out, int out_size, void* d_ws, size_t ws_size,
                              hipStream_t stream) {
  const float* keys    = (const float*)d_in[0];
  const float* queries = (const float*)d_in[1];
  const float* values  = (const float*)d_in[2];
  const float* WQ      = (const float*)d_in[3];
  const float* WK      = (const float*)d_in[4];
  const float* WV      = (const float*)d_in[5];
  float* out = (float*)d_out;
  u16* wsb = (u16*)d_ws;

  prep_kernel<<<dim3(1696), 256, 0, stream>>>(queries, keys, values, WQ, WK, WV, wsb, out);
  proj_kernel<<<dim3(32, 16, 3), 256, 0, stream>>>(wsb);
  stats_kernel<<<dim3(16, 32, 2), 256, 0, stream>>>(wsb);
  attn_kernel<<<dim3(16, 32, 2), 256, 0, stream>>>(wsb, out);
}

// Round 11
// 159.617 us; speedup vs baseline: 1.0864x; 1.0864x over previous
//
#include <hip/hip_runtime.h>
#include <hip/hip_bf16.h>

#define LL 2048
#define DM 512
#define SCALE 0.02209708691207961f   // 1/sqrt(2048)

typedef unsigned short u16;
typedef __attribute__((ext_vector_type(8))) short short8;    // 8 bf16 (4 VGPRs)
typedef __attribute__((ext_vector_type(4))) short short4v;   // 4 bf16 (2 VGPRs)
typedef __attribute__((ext_vector_type(4))) float f32x4;     // MFMA C/D

// ws layout (u16 element offsets), ~27 MB of the 256 MiB ws:
//  XAQ/XAK/XAV: bf16 inputs in proj-A-frag order [2][128 r16][16 kt][64 lane][8]
//  WB : bf16 weights in B-frag order [3][8][16 kt][4 nt][64 lane][8]
//  QA/KA: bf16 Q,K projections in frag order (Q pre-scaled by SCALE)
//  VB : bf16 V in PV-B-frag order (RAW; Sinv applied to P in attn)
//  S  : f32 Sinv [16][2048] (stats writes directly; no atomics anywhere)
#define XAQ_OFF 0u
#define XAK_OFF 2097152u
#define XAV_OFF 4194304u
#define WB_OFF  6291456u
#define QA_OFF  7077888u
#define KA_OFF  9175040u
#define VB_OFF  11272192u
#define S_OFF   13369344u    // float region, 32768 floats

__device__ __forceinline__ u16 f2bf(float f) {
  union { float f; unsigned u; } v; v.f = f;
  unsigned r = v.u + 0x7fff + ((v.u >> 16) & 1);   // RNE
  return (u16)(r >> 16);
}
__device__ __forceinline__ size_t frag_idx(int bh, int t64, int w, int c, int lane) {
  return ((((size_t)(bh * 32 + t64) * 4 + w) * 2 + c) * 64 + lane) * 8;
}
__device__ __forceinline__ size_t vb_idx(int bh, int kt, int w, int et, int lane) {
  return ((((size_t)(bh * 32 + kt) * 4 + w) * 4 + et) * 64 + lane) * 4;
}

// ---------------- prep: X -> frag order via LDS transpose; W -> B-frag order ----------------
__global__ __launch_bounds__(256) void prep_kernel(
    const float* __restrict__ queries, const float* __restrict__ keys,
    const float* __restrict__ values, const float* __restrict__ WQ,
    const float* __restrict__ WK, const float* __restrict__ WV,
    u16* __restrict__ wsb) {
  int t = threadIdx.x;
  int blk = blockIdx.x;
  if (blk < 768) {
    int tens = blk >> 8;                       // 0=Q,1=K,2=V
    int grp  = blk & 255;                      // b*128 + r16
    const float* src = (tens == 0 ? queries : tens == 1 ? keys : values) +
                       (size_t)grp * 16 * 512;
    __shared__ __align__(16) u16 Xs[16][520];
#pragma unroll
    for (int rep = 0; rep < 8; ++rep) {
      int f4 = t + rep * 256;                  // 0..2047
      int row = f4 >> 7, c4 = f4 & 127;
      float4 v = *(const float4*)(src + (size_t)row * 512 + c4 * 4);
      short4v o;
      o[0] = (short)f2bf(v.x); o[1] = (short)f2bf(v.y);
      o[2] = (short)f2bf(v.z); o[3] = (short)f2bf(v.w);
      *(short4v*)&Xs[row][c4 * 4] = o;
    }
    __syncthreads();
    u16* dst = wsb + (tens == 0 ? XAQ_OFF : tens == 1 ? XAK_OFF : XAV_OFF) +
               (size_t)grp * 16 * 64 * 8;
#pragma unroll
    for (int rep = 0; rep < 4; ++rep) {
      int o = t + rep * 256;                   // kt*64 + lane
      int kt = o >> 6, lane = o & 63;
      int quad = lane >> 4, l16 = lane & 15;
      short8 v = *(const short8*)&Xs[l16][kt * 32 + quad * 8];
      *(short8*)(dst + (size_t)o * 8) = v;
    }
  } else {
    int c2 = (blk - 768) * 256 + t;            // 0..98303
    int lane = c2 & 63;
    int nt = (c2 >> 6) & 3;
    int kt = (c2 >> 8) & 15;
    int h  = (c2 >> 12) & 7;
    int z  = c2 >> 15;
    int quad = lane >> 4, l16 = lane & 15;
    const float* W = (z == 0) ? WQ : (z == 1) ? WK : WV;
    const float* src = W + ((size_t)h * DM + kt * 32 + quad * 8) * 64 + nt * 16 + l16;
    short8 o;
#pragma unroll
    for (int j = 0; j < 8; ++j) o[j] = (short)f2bf(src[(size_t)j * 64]);
    *(short8*)(wsb + WB_OFF + (size_t)c2 * 8) = o;
  }
}

// ---------------- proj: barrier-free MFMA GEMM; coalesced frag-order epilogue via LDS ----------------
__global__ __launch_bounds__(256) void proj_kernel(u16* __restrict__ wsb) {
  int t = threadIdx.x;
  int lane = t & 63, w = t >> 6, quad = lane >> 4, l16 = lane & 15;
  int z = blockIdx.z, bh = blockIdx.y, b = bh >> 3, h = bh & 7;
  int QT = blockIdx.x;

  const u16* Bw = wsb + WB_OFF + ((size_t)(z * 8 + h) * 16) * 4 * 64 * 8;
  const u16* Ab = wsb + (z == 0 ? XAQ_OFF : z == 1 ? XAK_OFF : XAV_OFF) +
      (((size_t)b * 128 + QT * 4 + w) * 16) * 64 * 8;

  f32x4 acc[4];
#pragma unroll
  for (int nt = 0; nt < 4; ++nt) acc[nt] = (f32x4){0.f, 0.f, 0.f, 0.f};

#pragma unroll 4
  for (int kt = 0; kt < 16; ++kt) {
    short8 a = *(const short8*)(Ab + ((size_t)kt * 64 + lane) * 8);
#pragma unroll
    for (int nt = 0; nt < 4; ++nt) {
      short8 bb = *(const short8*)(Bw + (((size_t)kt * 4 + nt) * 64 + lane) * 8);
      acc[nt] = __builtin_amdgcn_mfma_f32_16x16x32_bf16(a, bb, acc[nt], 0, 0, 0);
    }
  }

  __shared__ float Cs[64][68];
  float sc = (z == 0) ? SCALE : 1.0f;
#pragma unroll
  for (int nt = 0; nt < 4; ++nt)
#pragma unroll
    for (int r = 0; r < 4; ++r)
      Cs[w * 16 + quad * 4 + r][nt * 16 + l16] = acc[nt][r] * sc;
  __syncthreads();

  if (z < 2) {
    u16* base = wsb + (z == 0 ? QA_OFF : KA_OFF);
#pragma unroll
    for (int c = 0; c < 2; ++c) {
      const float* srcr = &Cs[w * 16 + l16][c * 32 + quad * 8];
      short8 o;
#pragma unroll
      for (int j = 0; j < 8; ++j) o[j] = (short)f2bf(srcr[j]);
      *(short8*)(base + frag_idx(bh, QT, w, c, lane)) = o;
    }
  } else {
#pragma unroll
    for (int et = 0; et < 4; ++et) {
      short4v o;
#pragma unroll
      for (int j = 0; j < 4; ++j)
        o[j] = (short)f2bf(Cs[w * 16 + quad * 4 + j][et * 16 + l16]);
      *(short4v*)(wsb + VB_OFF + vb_idx(bh, QT, w, et, lane)) = o;
    }
  }
}

// ---------------- stats: k-split (32 cols/block); complete column sums in-block ----------------
// grid (x=bh, y=KT2): linear%8 == bh%8 -> all blocks of a bh on one XCD (L2-local QA re-reads).
__global__ __launch_bounds__(256, 4) void stats_kernel(u16* __restrict__ wsb) {
  int t = threadIdx.x;
  int lane = t & 63, w = t >> 6, quad = lane >> 4, l16 = lane & 15;
  int bh = blockIdx.x;
  int KT2 = blockIdx.y;                        // 32-k tile
  int t64 = KT2 >> 1, half = KT2 & 1;

  short8 ka[2][2];
#pragma unroll
  for (int mt = 0; mt < 2; ++mt)
#pragma unroll
    for (int c = 0; c < 2; ++c)
      ka[mt][c] = *(const short8*)(wsb + KA_OFF + frag_idx(bh, t64, half * 2 + mt, c, lane));

  float rs[2][4];
#pragma unroll
  for (int mt = 0; mt < 2; ++mt)
#pragma unroll
    for (int r = 0; r < 4; ++r) rs[mt][r] = 0.f;

  for (int qt = 0; qt < 32; ++qt) {
    short8 qb0 = *(const short8*)(wsb + QA_OFF + frag_idx(bh, qt, w, 0, lane));
    short8 qb1 = *(const short8*)(wsb + QA_OFF + frag_idx(bh, qt, w, 1, lane));
#pragma unroll
    for (int mt = 0; mt < 2; ++mt) {
      f32x4 y = (f32x4){0.f, 0.f, 0.f, 0.f};
      y = __builtin_amdgcn_mfma_f32_16x16x32_bf16(ka[mt][0], qb0, y, 0, 0, 0);
      y = __builtin_amdgcn_mfma_f32_16x16x32_bf16(ka[mt][1], qb1, y, 0, 0, 0);
#pragma unroll
      for (int r = 0; r < 4; ++r) rs[mt][r] += __expf(y[r]);
    }
  }
#pragma unroll
  for (int mt = 0; mt < 2; ++mt)
#pragma unroll
    for (int r = 0; r < 4; ++r) {
      rs[mt][r] += __shfl_xor(rs[mt][r], 1);
      rs[mt][r] += __shfl_xor(rs[mt][r], 2);
      rs[mt][r] += __shfl_xor(rs[mt][r], 4);
      rs[mt][r] += __shfl_xor(rs[mt][r], 8);
    }

  __shared__ float Sred[4][32];
  if (l16 == 0) {
#pragma unroll
    for (int mt = 0; mt < 2; ++mt)
#pragma unroll
      for (int r = 0; r < 4; ++r)
        Sred[w][mt * 16 + quad * 4 + r] = rs[mt][r];
  }
  __syncthreads();
  if (t < 32) {
    float s = Sred[0][t] + Sred[1][t] + Sred[2][t] + Sred[3][t];
    float* S = (float*)(wsb + S_OFF);
    S[(size_t)bh * LL + KT2 * 32 + t] = 1.0f / s;
  }
}

// ---------------- attn: q-split (32 rows/block); P in regs; 17.4 KB reduction LDS ----------------
// grid (x=bh, y=QT2): linear%8 == bh%8 -> XCD-local KA/VB re-reads.
__global__ __launch_bounds__(256, 4) void attn_kernel(const u16* __restrict__ wsb,
                                                      float* __restrict__ out) {
  int t = threadIdx.x;
  int lane = t & 63, w = t >> 6, quad = lane >> 4, l16 = lane & 15;
  int bh = blockIdx.x, b = bh >> 3, h = bh & 7;
  int QT2 = blockIdx.y;                        // 32-q tile
  int t64 = QT2 >> 1, half = QT2 & 1;
  const float* S = (const float*)(wsb + S_OFF) + (size_t)bh * LL;

  short8 qf[2][2];
#pragma unroll
  for (int nt = 0; nt < 2; ++nt)
#pragma unroll
    for (int c = 0; c < 2; ++c)
      qf[nt][c] = *(const short8*)(wsb + QA_OFF + frag_idx(bh, t64, half * 2 + nt, c, lane));

  f32x4 oacc[2][4];
#pragma unroll
  for (int nt = 0; nt < 2; ++nt)
#pragma unroll
    for (int et = 0; et < 4; ++et) oacc[nt][et] = (f32x4){0.f, 0.f, 0.f, 0.f};

  for (int kt = 0; kt < 32; ++kt) {
    short8 ka0 = *(const short8*)(wsb + KA_OFF + frag_idx(bh, kt, w, 0, lane));
    short8 ka1 = *(const short8*)(wsb + KA_OFF + frag_idx(bh, kt, w, 1, lane));
    short4v vb[4];
#pragma unroll
    for (int et = 0; et < 4; ++et)
      vb[et] = *(const short4v*)(wsb + VB_OFF + vb_idx(bh, kt, w, et, lane));
    float4 s4 = *(const float4*)(S + kt * 64 + w * 16 + quad * 4);   // Sinv, per-quad

#pragma unroll
    for (int nt = 0; nt < 2; ++nt) {
      f32x4 y = (f32x4){0.f, 0.f, 0.f, 0.f};
      y = __builtin_amdgcn_mfma_f32_16x16x32_bf16(ka0, qf[nt][0], y, 0, 0, 0);
      y = __builtin_amdgcn_mfma_f32_16x16x32_bf16(ka1, qf[nt][1], y, 0, 0, 0);
      short4v pa;
      pa[0] = (short)f2bf(__expf(y[0]) * s4.x);
      pa[1] = (short)f2bf(__expf(y[1]) * s4.y);
      pa[2] = (short)f2bf(__expf(y[2]) * s4.z);
      pa[3] = (short)f2bf(__expf(y[3]) * s4.w);
#pragma unroll
      for (int et = 0; et < 4; ++et)
        oacc[nt][et] = __builtin_amdgcn_mfma_f32_16x16x16bf16_1k(pa, vb[et], oacc[nt][et], 0, 0, 0);
    }
  }

  // 2-stage cross-wave k-reduction in 17.4 KB LDS (4 blocks/CU)
  __shared__ float red[2][32][68];
  if (w >= 2) {
#pragma unroll
    for (int nt = 0; nt < 2; ++nt)
#pragma unroll
      for (int et = 0; et < 4; ++et)
#pragma unroll
        for (int r = 0; r < 4; ++r)
          red[w - 2][nt * 16 + quad * 4 + r][et * 16 + l16] = oacc[nt][et][r];
  }
  __syncthreads();
  if (w < 2) {
#pragma unroll
    for (int nt = 0; nt < 2; ++nt)
#pragma unroll
      for (int et = 0; et < 4; ++et)
#pragma unroll
        for (int r = 0; r < 4; ++r)
          red[w][nt * 16 + quad * 4 + r][et * 16 + l16] += oacc[nt][et][r];
  }
  __syncthreads();
  // 32 output rows; each wave writes 8 (coalesced 256B per row-pair)
  float* og = out + ((size_t)b * LL + QT2 * 32 + w * 8) * 512 + h * 64;
#pragma unroll
  for (int i = 0; i < 8; ++i) {
    int row = w * 8 + i;
    float s = red[0][row][lane] + red[1][row][lane];
    og[(size_t)i * 512 + lane] = s;
  }
}

extern "C" void kernel_launch(void* const* d_in, const int* in_sizes, int n_in,
                              void* d_out, int out_size, void* d_ws, size_t ws_size,
                              hipStream_t stream) {
  const float* keys    = (const float*)d_in[0];
  const float* queries = (const float*)d_in[1];
  const float* values  = (const float*)d_in[2];
  const float* WQ      = (const float*)d_in[3];
  const float* WK      = (const float*)d_in[4];
  const float* WV      = (const float*)d_in[5];
  float* out = (float*)d_out;
  u16* wsb = (u16*)d_ws;

  prep_kernel<<<dim3(1152), 256, 0, stream>>>(queries, keys, values, WQ, WK, WV, wsb);
  proj_kernel<<<dim3(32, 16, 3), 256, 0, stream>>>(wsb);
  stats_kernel<<<dim3(16, 64), 256, 0, stream>>>(wsb);
  attn_kernel<<<dim3(16, 64), 256, 0, stream>>>(wsb, out);
}